// Round 4
// baseline (748.553 us; speedup 1.0000x reference)
//
#include <hip/hip_runtime.h>
#include <cstdint>

#define IN_CH 128
#define HID_CH 128
#define OUT_CH 64
#define NPART 64   // dst-range partition blocks for CSR build

typedef __attribute__((ext_vector_type(8))) short bf8_t;   // 8 bf16 = 4 VGPRs
typedef __attribute__((ext_vector_type(4))) float f4_t;

// ---------------------------------------------------------------------------
// bf16 helpers (RNE)
// ---------------------------------------------------------------------------
__device__ __forceinline__ uint32_t f_to_bf(float f) {
    union { float f; uint32_t u; } v; v.f = f;
    uint32_t u = v.u;
    return (u + 0x7fffu + ((u >> 16) & 1u)) >> 16;
}
__device__ __forceinline__ float bf_to_f(uint32_t h) {
    union { uint32_t u; float f; } v; v.u = h << 16; return v.f;
}
__device__ __forceinline__ float2 bf2_to_f2(uint32_t u) {
    union { uint32_t u; float f; } a, b;
    a.u = u << 16; b.u = u & 0xffff0000u;
    float2 r; r.x = a.f; r.y = b.f; return r;
}

// ---------------------------------------------------------------------------
// int64-vs-int32 edge layout detection (reference uses int64).
// ---------------------------------------------------------------------------
__device__ __forceinline__ int detect64(const int* __restrict__ e32) {
    return (e32[1] | e32[3] | e32[5] | e32[7]) == 0;
}
__device__ __forceinline__ int edge_at(const void* edges, int is64, int idx) {
    if (is64) return (int)((const long long*)edges)[idx];
    return ((const int*)edges)[idx];
}

// edge_index -> separate int32 src/dst arrays (one coalesced pass)
__global__ void edge_conv_kernel(const void* __restrict__ ei, int* __restrict__ s32,
                                 int* __restrict__ d32, int E) {
    int i = blockIdx.x * blockDim.x + threadIdx.x;
    if (i >= E) return;
    int is64 = detect64((const int*)ei);
    s32[i] = edge_at(ei, is64, i);
    d32[i] = edge_at(ei, is64, E + i);
}

// ---------------------------------------------------------------------------
// K1: per-block dst-range histogram + local exclusive scan + dinv.
// Block b owns dst in [b*R, b*R+lim). Streams whole dst array (L2-resident
// broadcast read), counts into LDS (single-writer: no cross-XCD bouncing).
// ---------------------------------------------------------------------------
__global__ __launch_bounds__(512) void count_scan_kernel(
    const int* __restrict__ d32, int* __restrict__ row_ptr, int* __restrict__ bsum,
    float* __restrict__ dinv, int n, int E, int R) {
    __shared__ int cnt[1024];
    __shared__ int sb[1024];
    int tid = threadIdx.x;
    int base = blockIdx.x * R;
    int lim = min(R, n - base);
    if (lim <= 0) { if (tid == 0) bsum[blockIdx.x] = 0; return; }
    for (int i = tid; i < 1024; i += 512) cnt[i] = 0;
    __syncthreads();
    int nIter = (E + 2047) / 2048;
    for (int it = 0; it < nIter; it++) {
        int g = (it * 512 + tid) * 4;
        if (g + 3 < E) {
            int4 d = *(const int4*)&d32[g];
            unsigned u0 = (unsigned)(d.x - base), u1 = (unsigned)(d.y - base);
            unsigned u2 = (unsigned)(d.z - base), u3 = (unsigned)(d.w - base);
            if (u0 < (unsigned)lim) atomicAdd(&cnt[u0], 1);
            if (u1 < (unsigned)lim) atomicAdd(&cnt[u1], 1);
            if (u2 < (unsigned)lim) atomicAdd(&cnt[u2], 1);
            if (u3 < (unsigned)lim) atomicAdd(&cnt[u3], 1);
        } else {
            for (int j = g; j < E; j++) {
                unsigned u = (unsigned)(d32[j] - base);
                if (u < (unsigned)lim) atomicAdd(&cnt[u], 1);
            }
        }
    }
    __syncthreads();
    for (int i = tid; i < lim; i += 512)
        dinv[base + i] = rsqrtf((float)(cnt[i] + 1));  // +1 = self-loop
    __syncthreads();
    int* a = cnt; int* b = sb;
#pragma unroll
    for (int s = 1; s < 1024; s <<= 1) {
        for (int i = tid; i < 1024; i += 512)
            b[i] = a[i] + ((i >= s) ? a[i - s] : 0);
        __syncthreads();
        int* t = a; a = b; b = t;
    }
    for (int i = tid; i < lim; i += 512)
        row_ptr[base + i] = (i > 0) ? a[i - 1] : 0;  // block-local exclusive
    if (tid == 0) bsum[blockIdx.x] = a[1023];
}

// K2: scan of NPART block totals -> boff; writes row_ptr[n] = grand total.
__global__ void scan_totals_kernel(const int* __restrict__ bsum, int* __restrict__ boff,
                                   int* __restrict__ row_ptr, int nb, int n) {
    int lane = threadIdx.x;  // 64 threads, nb <= 64
    int v = (lane < nb) ? bsum[lane] : 0;
    int incl = v;
#pragma unroll
    for (int off = 1; off < 64; off <<= 1) {
        int t = __shfl_up(incl, off);
        if (lane >= off) incl += t;
    }
    if (lane < nb) boff[lane] = incl - v;
    if (lane == 63) row_ptr[n] = incl;
}

// ---------------------------------------------------------------------------
// K3: per-block fill. Finalize row_ptr (+= boff[b]), mirror into LDS cursors,
// stream dst; matching edges append src into the block's own col segment.
// ---------------------------------------------------------------------------
__global__ __launch_bounds__(512) void fill_local_kernel(
    const int* __restrict__ s32, const int* __restrict__ d32,
    int* __restrict__ row_ptr, const int* __restrict__ boff,
    int* __restrict__ col, int n, int E, int R) {
    __shared__ int cur[1024];
    int tid = threadIdx.x;
    int base = blockIdx.x * R;
    int lim = min(R, n - base);
    if (lim <= 0) return;
    int bo = boff[blockIdx.x];
    for (int i = tid; i < lim; i += 512) {
        int v = row_ptr[base + i] + bo;
        row_ptr[base + i] = v;
        cur[i] = v;
    }
    __syncthreads();
    int nIter = (E + 2047) / 2048;
    for (int it = 0; it < nIter; it++) {
        int g = (it * 512 + tid) * 4;
        if (g + 3 < E) {
            int4 d = *(const int4*)&d32[g];
            unsigned u0 = (unsigned)(d.x - base), u1 = (unsigned)(d.y - base);
            unsigned u2 = (unsigned)(d.z - base), u3 = (unsigned)(d.w - base);
            if (u0 < (unsigned)lim) { int p = atomicAdd(&cur[u0], 1); col[p] = s32[g + 0]; }
            if (u1 < (unsigned)lim) { int p = atomicAdd(&cur[u1], 1); col[p] = s32[g + 1]; }
            if (u2 < (unsigned)lim) { int p = atomicAdd(&cur[u2], 1); col[p] = s32[g + 2]; }
            if (u3 < (unsigned)lim) { int p = atomicAdd(&cur[u3], 1); col[p] = s32[g + 3]; }
        } else {
            for (int j = g; j < E; j++) {
                unsigned u = (unsigned)(d32[j] - base);
                if (u < (unsigned)lim) { int p = atomicAdd(&cur[u], 1); col[p] = s32[j]; }
            }
        }
    }
}

// ---------------------------------------------------------------------------
// All three W matrices -> MFMA B-operand fragment order, hi/lo bf16 split.
// ---------------------------------------------------------------------------
__global__ void w_split_all(const float* __restrict__ W1, const float* __restrict__ W2,
                            const float* __restrict__ W3,
                            uint16_t* w1h, uint16_t* w1l, uint16_t* w2h, uint16_t* w2l,
                            uint16_t* w3h, uint16_t* w3l) {
    int idx = blockIdx.x * blockDim.x + threadIdx.x;
    const float* W; uint16_t* oh; uint16_t* ol; int FOUT; int e;
    if (idx < 16384)      { W = W1; oh = w1h; ol = w1l; FOUT = 128; e = idx; }
    else if (idx < 32768) { W = W2; oh = w2h; ol = w2l; FOUT = 128; e = idx - 16384; }
    else if (idx < 40960) { W = W3; oh = w3h; ol = w3l; FOUT = 64;  e = idx - 32768; }
    else return;
    int j = e & 7;
    int lane = (e >> 3) & 63;
    int rem = e >> 9;
    int NT = FOUT >> 4;
    int nt = rem % NT, kc = rem / NT;
    int k = kc * 32 + ((lane >> 4) << 3) + j;
    int c = nt * 16 + (lane & 15);
    float v = W[(size_t)k * FOUT + c];
    uint32_t h = f_to_bf(v);
    uint32_t l = f_to_bf(v - bf_to_f(h));
    oh[e] = (uint16_t)h;
    ol[e] = (uint16_t)l;
}

// ---------------------------------------------------------------------------
// MFMA GEMM: Y[i][:] = (A[i][:] @ W) * dinv[i], fp32-accuracy via 3-term
// bf16 split. K = 128. Block = 4 waves, no LDS. AF32 fuses the x-split.
// ---------------------------------------------------------------------------
template <int FOUT, bool BFOUT, bool AF32>
__global__ __launch_bounds__(256) void gemm_mfma(
    const void* __restrict__ A0, const uint16_t* __restrict__ Alo,
    const uint16_t* __restrict__ Wfhi, const uint16_t* __restrict__ Wflo,
    const float* __restrict__ dinv, void* __restrict__ Yv, int n) {
    constexpr int NT = FOUT / 16;
    constexpr int NTW = 2;
    int wid = threadIdx.x >> 6;
    int lane = threadIdx.x & 63;
    int cp, tile0, tstride;
    if (FOUT == 128) { cp = wid;     tile0 = blockIdx.x;                  tstride = gridDim.x; }
    else             { cp = wid & 1; tile0 = blockIdx.x * 2 + (wid >> 1); tstride = gridDim.x * 2; }
    int ntiles = (n + 15) >> 4;

    bf8_t wh[NTW][4], wl[NTW][4];
#pragma unroll
    for (int t = 0; t < NTW; t++) {
        int nt = cp * NTW + t;
#pragma unroll
        for (int kc = 0; kc < 4; kc++) {
            size_t b = ((size_t)(kc * NT + nt) * 64 + lane) * 8;
            wh[t][kc] = *(const bf8_t*)&Wfhi[b];
            wl[t][kc] = *(const bf8_t*)&Wflo[b];
        }
    }
    int row_in = lane & 15;
    int koff = (lane >> 4) << 3;
    int colb = lane & 15;
    int rq = (lane >> 4) << 2;

    for (int tile = tile0; tile < ntiles; tile += tstride) {
        int R = tile << 4;
        int arow = R + row_in; if (arow >= n) arow = n - 1;
        bf8_t ah[4], al[4];
        if (AF32) {
            const float* ap = (const float*)A0 + (size_t)arow * 128 + koff;
#pragma unroll
            for (int kc = 0; kc < 4; kc++) {
                float4 pv = *(const float4*)(ap + kc * 32);
                float4 qv = *(const float4*)(ap + kc * 32 + 4);
                float vv[8] = {pv.x, pv.y, pv.z, pv.w, qv.x, qv.y, qv.z, qv.w};
#pragma unroll
                for (int j = 0; j < 8; j++) {
                    uint32_t h = f_to_bf(vv[j]);
                    ah[kc][j] = (short)h;
                    al[kc][j] = (short)f_to_bf(vv[j] - bf_to_f(h));
                }
            }
        } else {
            const uint16_t* ap_hi = (const uint16_t*)A0 + (size_t)arow * 128 + koff;
            const uint16_t* ap_lo = Alo + (size_t)arow * 128 + koff;
#pragma unroll
            for (int kc = 0; kc < 4; kc++) {
                ah[kc] = *(const bf8_t*)(ap_hi + kc * 32);
                al[kc] = *(const bf8_t*)(ap_lo + kc * 32);
            }
        }
        f4_t acc[NTW];
#pragma unroll
        for (int t = 0; t < NTW; t++) acc[t] = (f4_t){0.f, 0.f, 0.f, 0.f};
#pragma unroll
        for (int kc = 0; kc < 4; kc++) {
#pragma unroll
            for (int t = 0; t < NTW; t++) {
                acc[t] = __builtin_amdgcn_mfma_f32_16x16x32_bf16(ah[kc], wh[t][kc], acc[t], 0, 0, 0);
                acc[t] = __builtin_amdgcn_mfma_f32_16x16x32_bf16(ah[kc], wl[t][kc], acc[t], 0, 0, 0);
                acc[t] = __builtin_amdgcn_mfma_f32_16x16x32_bf16(al[kc], wh[t][kc], acc[t], 0, 0, 0);
            }
        }
#pragma unroll
        for (int t = 0; t < NTW; t++) {
            int c = (cp * NTW + t) * 16 + colb;
#pragma unroll
            for (int r = 0; r < 4; r++) {
                int row = R + rq + r;
                if (row < n) {
                    float v = acc[t][r] * dinv[row];
                    if (BFOUT)
                        ((uint16_t*)Yv)[(size_t)row * FOUT + c] = (uint16_t)f_to_bf(v);
                    else
                        ((float*)Yv)[(size_t)row * FOUT + c] = v;
                }
            }
        }
    }
}

// ---------------------------------------------------------------------------
// out[i] = maybe_relu( dinv[i] * (y[i] + sum_{e: dst=i} y[col[e]]) + bias )
// One wave per node; bf16 gathers; 8 independent accumulator chains.
// ---------------------------------------------------------------------------
template <int CH, bool RELU, int OUTMODE>
__global__ __launch_bounds__(256) void aggregate_kernel(
    const void* __restrict__ Yv, const int* __restrict__ row_ptr,
    const int* __restrict__ col, const float* __restrict__ dinv,
    const float* __restrict__ bias, void* __restrict__ out0,
    void* __restrict__ out1, int n) {
    int w = blockIdx.x * 4 + (threadIdx.x >> 6);
    int lane = threadIdx.x & 63;
    if (w >= n) return;
    constexpr int V = CH / 64;

    auto loadrow = [&](int node) -> float2 {
        if (V == 2) {
            uint32_t u = *((const uint32_t*)Yv + (size_t)node * (CH / 2) + lane);
            return bf2_to_f2(u);
        } else {
            uint32_t u = ((const uint16_t*)Yv)[(size_t)node * CH + lane];
            float2 r; r.x = bf_to_f(u); r.y = 0.f;
            return r;
        }
    };

    float2 acc[8];
#pragma unroll
    for (int t = 0; t < 8; t++) acc[t] = (float2){0.f, 0.f};
    acc[0] = loadrow(w);  // self-loop term
    int start = row_ptr[w], end = row_ptr[w + 1];
    for (int base = start; base < end; base += 64) {
        int cnt = min(64, end - base);
        int sv = (base + lane < end) ? col[base + lane] : 0;
        int j = 0;
        for (; j + 8 <= cnt; j += 8) {
            int s[8];
#pragma unroll
            for (int t = 0; t < 8; t++) s[t] = __shfl(sv, j + t);
            float2 v[8];
#pragma unroll
            for (int t = 0; t < 8; t++) v[t] = loadrow(s[t]);
#pragma unroll
            for (int t = 0; t < 8; t++) { acc[t].x += v[t].x; acc[t].y += v[t].y; }
        }
        for (; j + 2 <= cnt; j += 2) {
            int s0 = __shfl(sv, j), s1 = __shfl(sv, j + 1);
            float2 v0 = loadrow(s0), v1 = loadrow(s1);
            acc[0].x += v0.x; acc[0].y += v0.y;
            acc[1].x += v1.x; acc[1].y += v1.y;
        }
        for (; j < cnt; j++) {
            int s = __shfl(sv, j);
            float2 v = loadrow(s);
            acc[0].x += v.x; acc[0].y += v.y;
        }
    }
    float sx = ((acc[0].x + acc[1].x) + (acc[2].x + acc[3].x)) +
               ((acc[4].x + acc[5].x) + (acc[6].x + acc[7].x));
    float sy = ((acc[0].y + acc[1].y) + (acc[2].y + acc[3].y)) +
               ((acc[4].y + acc[5].y) + (acc[6].y + acc[7].y));
    float di = dinv[w];
    if (V == 2) {
        float ox = sx * di + bias[lane * 2];
        float oy = sy * di + bias[lane * 2 + 1];
        if (RELU) { ox = fmaxf(ox, 0.f); oy = fmaxf(oy, 0.f); }
        if (OUTMODE == 0) {
            float2 o; o.x = ox; o.y = oy;
            *(float2*)((float*)out0 + (size_t)w * CH + lane * 2) = o;
        } else {
            uint32_t h0 = f_to_bf(ox), h1 = f_to_bf(oy);
            uint32_t l0 = f_to_bf(ox - bf_to_f(h0)), l1 = f_to_bf(oy - bf_to_f(h1));
            ((uint32_t*)out0)[(size_t)w * (CH / 2) + lane] = h0 | (h1 << 16);
            ((uint32_t*)out1)[(size_t)w * (CH / 2) + lane] = l0 | (l1 << 16);
        }
    } else {
        float ox = sx * di + bias[lane];
        if (RELU) ox = fmaxf(ox, 0.f);
        ((float*)out0)[(size_t)w * CH + lane] = ox;
    }
}

extern "C" void kernel_launch(void* const* d_in, const int* in_sizes, int n_in,
                              void* d_out, int out_size, void* d_ws, size_t ws_size,
                              hipStream_t stream) {
    const float* x  = (const float*)d_in[0];
    const void*  ei = d_in[1];
    const float* W1 = (const float*)d_in[2];
    const float* b1 = (const float*)d_in[3];
    const float* W2 = (const float*)d_in[4];
    const float* b2 = (const float*)d_in[5];
    const float* W3 = (const float*)d_in[6];
    const float* b3 = (const float*)d_in[7];
    int n = in_sizes[0] / IN_CH;   // 50000
    int E = in_sizes[1] / 2;       // 800000

    char* p = (char*)d_ws;
    auto carve = [&](size_t bytes) {
        char* r = p;
        p += (bytes + 255) & ~(size_t)255;
        return r;
    };
    float*    dinv    = (float*)carve((size_t)n * 4);
    int*      row_ptr = (int*)carve((size_t)(n + 1) * 4);
    int*      bsum    = (int*)carve(NPART * 4);
    int*      boff    = (int*)carve(NPART * 4);
    int*      col     = (int*)carve((size_t)E * 4);
    uint16_t* ahi     = (uint16_t*)carve((size_t)n * 128 * 2);
    uint16_t* alo     = (uint16_t*)carve((size_t)n * 128 * 2);
    void*     y       = (void*)carve((size_t)n * 128 * 2);  // bf16 y; aliases s32/d32
    uint16_t* w1h     = (uint16_t*)carve(128 * 128 * 2);
    uint16_t* w1l     = (uint16_t*)carve(128 * 128 * 2);
    uint16_t* w2h     = (uint16_t*)carve(128 * 128 * 2);
    uint16_t* w2l     = (uint16_t*)carve(128 * 128 * 2);
    uint16_t* w3h     = (uint16_t*)carve(128 * 64 * 2);
    uint16_t* w3l     = (uint16_t*)carve(128 * 64 * 2);
    // s32/d32 alias y: dead after fill_local; y first written by gemm L1 later.
    int* s32 = (int*)y;
    int* d32 = (int*)y + E;

    int R = (n + NPART - 1) / NPART;
    const int tpb = 256;

    // ---- CSR + norm build (single-writer partitions, no global atomics) ----
    edge_conv_kernel<<<(E + tpb - 1) / tpb, tpb, 0, stream>>>(ei, s32, d32, E);
    count_scan_kernel<<<NPART, 512, 0, stream>>>(d32, row_ptr, bsum, dinv, n, E, R);
    scan_totals_kernel<<<1, 64, 0, stream>>>(bsum, boff, row_ptr, NPART, n);
    fill_local_kernel<<<NPART, 512, 0, stream>>>(s32, d32, row_ptr, boff, col, n, E, R);
    w_split_all<<<160, tpb, 0, stream>>>(W1, W2, W3, w1h, w1l, w2h, w2l, w3h, w3l);

    int gb = 782;
    int ab = (n + 3) / 4;

    // ---- layer 1 (fp32 x, in-register split) ----
    gemm_mfma<128, true, true><<<gb, 256, 0, stream>>>(x, nullptr, w1h, w1l, dinv, y, n);
    aggregate_kernel<128, true, 1><<<ab, 256, 0, stream>>>(y, row_ptr, col, dinv, b1, ahi, alo, n);
    // ---- layer 2 ----
    gemm_mfma<128, true, false><<<gb, 256, 0, stream>>>(ahi, alo, w2h, w2l, dinv, y, n);
    aggregate_kernel<128, true, 1><<<ab, 256, 0, stream>>>(y, row_ptr, col, dinv, b2, ahi, alo, n);
    // ---- layer 3 (64 ch, bf16 y, no relu) ----
    gemm_mfma<64, true, false><<<gb, 256, 0, stream>>>(ahi, alo, w3h, w3l, dinv, y, n);
    aggregate_kernel<64, false, 0><<<ab, 256, 0, stream>>>(y, row_ptr, col, dinv, b3, d_out, nullptr, n);
}

// Round 5
// 283.167 us; speedup vs baseline: 2.6435x; 2.6435x over previous
//
#include <hip/hip_runtime.h>
#include <cstdint>

#define IN_CH 128
#define HID_CH 128
#define OUT_CH 64
#define NB 49        // dst buckets: bucket = dst >> 10, n < 50176
#define CAP 32768    // slots per bucket (expected fill ~16.3k, uniform random)
#define CHUNK 2048   // edges per scatter block

typedef __attribute__((ext_vector_type(8))) short bf8_t;   // 8 bf16 = 4 VGPRs
typedef __attribute__((ext_vector_type(4))) float f4_t;

// ---------------------------------------------------------------------------
// bf16 helpers (RNE)
// ---------------------------------------------------------------------------
__device__ __forceinline__ uint32_t f_to_bf(float f) {
    union { float f; uint32_t u; } v; v.f = f;
    uint32_t u = v.u;
    return (u + 0x7fffu + ((u >> 16) & 1u)) >> 16;
}
__device__ __forceinline__ float bf_to_f(uint32_t h) {
    union { uint32_t u; float f; } v; v.u = h << 16; return v.f;
}
__device__ __forceinline__ float2 bf2_to_f2(uint32_t u) {
    union { uint32_t u; float f; } a, b;
    a.u = u << 16; b.u = u & 0xffff0000u;
    float2 r; r.x = a.f; r.y = b.f; return r;
}

// ---------------------------------------------------------------------------
// int64-vs-int32 edge layout detection (reference uses int64).
// ---------------------------------------------------------------------------
__device__ __forceinline__ int detect64(const int* __restrict__ e32) {
    return (e32[1] | e32[3] | e32[5] | e32[7]) == 0;
}
__device__ __forceinline__ int edge_at(const void* edges, int is64, int idx) {
    if (is64) return (int)((const long long*)edges)[idx];
    return ((const int*)edges)[idx];
}

// bucket_cur[b] = b * CAP
__global__ void init_cursors_kernel(int* __restrict__ bucket_cur) {
    int t = threadIdx.x;
    if (t < 64) bucket_cur[t] = t * CAP;
}

// ---------------------------------------------------------------------------
// Scatter: each block owns a CHUNK of edges. LDS histogram over NB buckets,
// one global atomicAdd per (block,bucket) to reserve a contiguous run, then
// write (src,dst) into the bucket region. dst kept in registers between the
// two passes; src loaded only in pass 2.
// ---------------------------------------------------------------------------
__global__ __launch_bounds__(256) void scatter_kernel(
    const void* __restrict__ ei, int* __restrict__ bucket_cur,
    int2* __restrict__ buckets, int E) {
    __shared__ int cnt[64];
    int tid = threadIdx.x;
    int base = blockIdx.x * CHUNK;
    int is64 = detect64((const int*)ei);
    if (tid < 64) cnt[tid] = 0;
    __syncthreads();
    int dloc[8];
#pragma unroll
    for (int it = 0; it < 8; it++) {
        int i = base + it * 256 + tid;
        int d = (i < E) ? edge_at(ei, is64, E + i) : -1;
        dloc[it] = d;
        if (d >= 0) atomicAdd(&cnt[d >> 10], 1);
    }
    __syncthreads();
    if (tid < 64) {
        int v = cnt[tid];
        cnt[tid] = atomicAdd(&bucket_cur[tid], v);  // absolute base of this block's run
    }
    __syncthreads();
#pragma unroll
    for (int it = 0; it < 8; it++) {
        int i = base + it * 256 + tid;
        if (dloc[it] >= 0) {
            int s = edge_at(ei, is64, i);
            int p = atomicAdd(&cnt[dloc[it] >> 10], 1);
            buckets[p] = make_int2(s, dloc[it]);
        }
    }
}

// ---------------------------------------------------------------------------
// Per-bucket CSR phase 1: histogram over the bucket's 1024 nodes, dinv,
// block-local exclusive scan, block total.
// ---------------------------------------------------------------------------
__global__ __launch_bounds__(512) void csr_local_kernel(
    const int2* __restrict__ buckets, const int* __restrict__ bucket_cur,
    int* __restrict__ row_ptr, int* __restrict__ bsum, float* __restrict__ dinv, int n) {
    __shared__ int cnt[1024];
    __shared__ int sb[1024];
    int b = blockIdx.x, tid = threadIdx.x;
    int base = b << 10;
    int lim = min(1024, n - base);
    if (lim <= 0) { if (tid == 0) bsum[b] = 0; return; }
    int ecnt = bucket_cur[b] - b * CAP;
    const int2* ebase = buckets + (size_t)b * CAP;
    for (int i = tid; i < 1024; i += 512) cnt[i] = 0;
    __syncthreads();
    for (int i = tid; i < ecnt; i += 512)
        atomicAdd(&cnt[ebase[i].y - base], 1);
    __syncthreads();
    for (int i = tid; i < lim; i += 512)
        dinv[base + i] = rsqrtf((float)(cnt[i] + 1));  // +1 = self-loop
    __syncthreads();
    int* a = cnt; int* s = sb;
    for (int st = 1; st < 1024; st <<= 1) {
        for (int i = tid; i < 1024; i += 512)
            s[i] = a[i] + ((i >= st) ? a[i - st] : 0);
        __syncthreads();
        int* t = a; a = s; s = t;
    }
    for (int i = tid; i < lim; i += 512)
        row_ptr[base + i] = (i > 0) ? a[i - 1] : 0;  // block-local exclusive
    if (tid == 0) bsum[b] = a[1023];
}

// Cross-bucket scan of NB totals -> boff; row_ptr[n] = grand total.
__global__ void scan_totals_kernel(const int* __restrict__ bsum, int* __restrict__ boff,
                                   int* __restrict__ row_ptr, int nb, int n) {
    int lane = threadIdx.x;  // 64 threads, nb <= 64
    int v = (lane < nb) ? bsum[lane] : 0;
    int incl = v;
#pragma unroll
    for (int off = 1; off < 64; off <<= 1) {
        int t = __shfl_up(incl, off);
        if (lane >= off) incl += t;
    }
    if (lane < nb) boff[lane] = incl - v;
    if (lane == 63) row_ptr[n] = incl;
}

// ---------------------------------------------------------------------------
// Per-bucket CSR phase 2: finalize row_ptr (+= boff), LDS cursors, fill col.
// col writes land in this block's contiguous segment -> single writer.
// ---------------------------------------------------------------------------
__global__ __launch_bounds__(512) void fill_bucket_kernel(
    const int2* __restrict__ buckets, const int* __restrict__ bucket_cur,
    int* __restrict__ row_ptr, const int* __restrict__ boff,
    int* __restrict__ col, int n) {
    __shared__ int cur[1024];
    int b = blockIdx.x, tid = threadIdx.x;
    int base = b << 10;
    int lim = min(1024, n - base);
    if (lim <= 0) return;
    int ecnt = bucket_cur[b] - b * CAP;
    const int2* ebase = buckets + (size_t)b * CAP;
    int bo = boff[b];
    for (int i = tid; i < lim; i += 512) {
        int v = row_ptr[base + i] + bo;
        row_ptr[base + i] = v;
        cur[i] = v;
    }
    __syncthreads();
    for (int i = tid; i < ecnt; i += 512) {
        int2 e = ebase[i];
        int p = atomicAdd(&cur[e.y - base], 1);
        col[p] = e.x;
    }
}

// ---------------------------------------------------------------------------
// All three W matrices -> MFMA B-operand fragment order, hi/lo bf16 split.
// ---------------------------------------------------------------------------
__global__ void w_split_all(const float* __restrict__ W1, const float* __restrict__ W2,
                            const float* __restrict__ W3,
                            uint16_t* w1h, uint16_t* w1l, uint16_t* w2h, uint16_t* w2l,
                            uint16_t* w3h, uint16_t* w3l) {
    int idx = blockIdx.x * blockDim.x + threadIdx.x;
    const float* W; uint16_t* oh; uint16_t* ol; int FOUT; int e;
    if (idx < 16384)      { W = W1; oh = w1h; ol = w1l; FOUT = 128; e = idx; }
    else if (idx < 32768) { W = W2; oh = w2h; ol = w2l; FOUT = 128; e = idx - 16384; }
    else if (idx < 40960) { W = W3; oh = w3h; ol = w3l; FOUT = 64;  e = idx - 32768; }
    else return;
    int j = e & 7;
    int lane = (e >> 3) & 63;
    int rem = e >> 9;
    int NT = FOUT >> 4;
    int nt = rem % NT, kc = rem / NT;
    int k = kc * 32 + ((lane >> 4) << 3) + j;
    int c = nt * 16 + (lane & 15);
    float v = W[(size_t)k * FOUT + c];
    uint32_t h = f_to_bf(v);
    uint32_t l = f_to_bf(v - bf_to_f(h));
    oh[e] = (uint16_t)h;
    ol[e] = (uint16_t)l;
}

// ---------------------------------------------------------------------------
// MFMA GEMM: Y[i][:] = (A[i][:] @ W) * dinv[i], fp32-accuracy via 3-term
// bf16 split. K = 128. Block = 4 waves, no LDS. AF32 fuses the x-split.
// ---------------------------------------------------------------------------
template <int FOUT, bool BFOUT, bool AF32>
__global__ __launch_bounds__(256) void gemm_mfma(
    const void* __restrict__ A0, const uint16_t* __restrict__ Alo,
    const uint16_t* __restrict__ Wfhi, const uint16_t* __restrict__ Wflo,
    const float* __restrict__ dinv, void* __restrict__ Yv, int n) {
    constexpr int NT = FOUT / 16;
    constexpr int NTW = 2;
    int wid = threadIdx.x >> 6;
    int lane = threadIdx.x & 63;
    int cp, tile0, tstride;
    if (FOUT == 128) { cp = wid;     tile0 = blockIdx.x;                  tstride = gridDim.x; }
    else             { cp = wid & 1; tile0 = blockIdx.x * 2 + (wid >> 1); tstride = gridDim.x * 2; }
    int ntiles = (n + 15) >> 4;

    bf8_t wh[NTW][4], wl[NTW][4];
#pragma unroll
    for (int t = 0; t < NTW; t++) {
        int nt = cp * NTW + t;
#pragma unroll
        for (int kc = 0; kc < 4; kc++) {
            size_t b = ((size_t)(kc * NT + nt) * 64 + lane) * 8;
            wh[t][kc] = *(const bf8_t*)&Wfhi[b];
            wl[t][kc] = *(const bf8_t*)&Wflo[b];
        }
    }
    int row_in = lane & 15;
    int koff = (lane >> 4) << 3;
    int colb = lane & 15;
    int rq = (lane >> 4) << 2;

    for (int tile = tile0; tile < ntiles; tile += tstride) {
        int R = tile << 4;
        int arow = R + row_in; if (arow >= n) arow = n - 1;
        bf8_t ah[4], al[4];
        if (AF32) {
            const float* ap = (const float*)A0 + (size_t)arow * 128 + koff;
#pragma unroll
            for (int kc = 0; kc < 4; kc++) {
                float4 pv = *(const float4*)(ap + kc * 32);
                float4 qv = *(const float4*)(ap + kc * 32 + 4);
                float vv[8] = {pv.x, pv.y, pv.z, pv.w, qv.x, qv.y, qv.z, qv.w};
#pragma unroll
                for (int j = 0; j < 8; j++) {
                    uint32_t h = f_to_bf(vv[j]);
                    ah[kc][j] = (short)h;
                    al[kc][j] = (short)f_to_bf(vv[j] - bf_to_f(h));
                }
            }
        } else {
            const uint16_t* ap_hi = (const uint16_t*)A0 + (size_t)arow * 128 + koff;
            const uint16_t* ap_lo = Alo + (size_t)arow * 128 + koff;
#pragma unroll
            for (int kc = 0; kc < 4; kc++) {
                ah[kc] = *(const bf8_t*)(ap_hi + kc * 32);
                al[kc] = *(const bf8_t*)(ap_lo + kc * 32);
            }
        }
        f4_t acc[NTW];
#pragma unroll
        for (int t = 0; t < NTW; t++) acc[t] = (f4_t){0.f, 0.f, 0.f, 0.f};
#pragma unroll
        for (int kc = 0; kc < 4; kc++) {
#pragma unroll
            for (int t = 0; t < NTW; t++) {
                acc[t] = __builtin_amdgcn_mfma_f32_16x16x32_bf16(ah[kc], wh[t][kc], acc[t], 0, 0, 0);
                acc[t] = __builtin_amdgcn_mfma_f32_16x16x32_bf16(ah[kc], wl[t][kc], acc[t], 0, 0, 0);
                acc[t] = __builtin_amdgcn_mfma_f32_16x16x32_bf16(al[kc], wh[t][kc], acc[t], 0, 0, 0);
            }
        }
#pragma unroll
        for (int t = 0; t < NTW; t++) {
            int c = (cp * NTW + t) * 16 + colb;
#pragma unroll
            for (int r = 0; r < 4; r++) {
                int row = R + rq + r;
                if (row < n) {
                    float v = acc[t][r] * dinv[row];
                    if (BFOUT)
                        ((uint16_t*)Yv)[(size_t)row * FOUT + c] = (uint16_t)f_to_bf(v);
                    else
                        ((float*)Yv)[(size_t)row * FOUT + c] = v;
                }
            }
        }
    }
}

// ---------------------------------------------------------------------------
// out[i] = maybe_relu( dinv[i] * (y[i] + sum_{e: dst=i} y[col[e]]) + bias )
// One wave per node; bf16 gathers; 8 independent accumulator chains.
// ---------------------------------------------------------------------------
template <int CH, bool RELU, int OUTMODE>
__global__ __launch_bounds__(256) void aggregate_kernel(
    const void* __restrict__ Yv, const int* __restrict__ row_ptr,
    const int* __restrict__ col, const float* __restrict__ dinv,
    const float* __restrict__ bias, void* __restrict__ out0,
    void* __restrict__ out1, int n) {
    int w = blockIdx.x * 4 + (threadIdx.x >> 6);
    int lane = threadIdx.x & 63;
    if (w >= n) return;
    constexpr int V = CH / 64;

    auto loadrow = [&](int node) -> float2 {
        if (V == 2) {
            uint32_t u = *((const uint32_t*)Yv + (size_t)node * (CH / 2) + lane);
            return bf2_to_f2(u);
        } else {
            uint32_t u = ((const uint16_t*)Yv)[(size_t)node * CH + lane];
            float2 r; r.x = bf_to_f(u); r.y = 0.f;
            return r;
        }
    };

    float2 acc[8];
#pragma unroll
    for (int t = 0; t < 8; t++) acc[t] = (float2){0.f, 0.f};
    acc[0] = loadrow(w);  // self-loop term
    int start = row_ptr[w], end = row_ptr[w + 1];
    for (int base = start; base < end; base += 64) {
        int cnt = min(64, end - base);
        int sv = (base + lane < end) ? col[base + lane] : 0;
        int j = 0;
        for (; j + 8 <= cnt; j += 8) {
            int s[8];
#pragma unroll
            for (int t = 0; t < 8; t++) s[t] = __shfl(sv, j + t);
            float2 v[8];
#pragma unroll
            for (int t = 0; t < 8; t++) v[t] = loadrow(s[t]);
#pragma unroll
            for (int t = 0; t < 8; t++) { acc[t].x += v[t].x; acc[t].y += v[t].y; }
        }
        for (; j + 2 <= cnt; j += 2) {
            int s0 = __shfl(sv, j), s1 = __shfl(sv, j + 1);
            float2 v0 = loadrow(s0), v1 = loadrow(s1);
            acc[0].x += v0.x; acc[0].y += v0.y;
            acc[1].x += v1.x; acc[1].y += v1.y;
        }
        for (; j < cnt; j++) {
            int s = __shfl(sv, j);
            float2 v = loadrow(s);
            acc[0].x += v.x; acc[0].y += v.y;
        }
    }
    float sx = ((acc[0].x + acc[1].x) + (acc[2].x + acc[3].x)) +
               ((acc[4].x + acc[5].x) + (acc[6].x + acc[7].x));
    float sy = ((acc[0].y + acc[1].y) + (acc[2].y + acc[3].y)) +
               ((acc[4].y + acc[5].y) + (acc[6].y + acc[7].y));
    float di = dinv[w];
    if (V == 2) {
        float ox = sx * di + bias[lane * 2];
        float oy = sy * di + bias[lane * 2 + 1];
        if (RELU) { ox = fmaxf(ox, 0.f); oy = fmaxf(oy, 0.f); }
        if (OUTMODE == 0) {
            float2 o; o.x = ox; o.y = oy;
            *(float2*)((float*)out0 + (size_t)w * CH + lane * 2) = o;
        } else {
            uint32_t h0 = f_to_bf(ox), h1 = f_to_bf(oy);
            uint32_t l0 = f_to_bf(ox - bf_to_f(h0)), l1 = f_to_bf(oy - bf_to_f(h1));
            ((uint32_t*)out0)[(size_t)w * (CH / 2) + lane] = h0 | (h1 << 16);
            ((uint32_t*)out1)[(size_t)w * (CH / 2) + lane] = l0 | (l1 << 16);
        }
    } else {
        float ox = sx * di + bias[lane];
        if (RELU) ox = fmaxf(ox, 0.f);
        ((float*)out0)[(size_t)w * CH + lane] = ox;
    }
}

extern "C" void kernel_launch(void* const* d_in, const int* in_sizes, int n_in,
                              void* d_out, int out_size, void* d_ws, size_t ws_size,
                              hipStream_t stream) {
    const float* x  = (const float*)d_in[0];
    const void*  ei = d_in[1];
    const float* W1 = (const float*)d_in[2];
    const float* b1 = (const float*)d_in[3];
    const float* W2 = (const float*)d_in[4];
    const float* b2 = (const float*)d_in[5];
    const float* W3 = (const float*)d_in[6];
    const float* b3 = (const float*)d_in[7];
    int n = in_sizes[0] / IN_CH;   // 50000
    int E = in_sizes[1] / 2;       // 800000

    char* p = (char*)d_ws;
    auto carve = [&](size_t bytes) {
        char* r = p;
        p += (bytes + 255) & ~(size_t)255;
        return r;
    };
    float*    dinv       = (float*)carve((size_t)n * 4);
    int*      row_ptr    = (int*)carve((size_t)(n + 1) * 4);
    int*      bsum       = (int*)carve(64 * 4);
    int*      boff       = (int*)carve(64 * 4);
    int*      bucket_cur = (int*)carve(64 * 4);
    int*      col        = (int*)carve((size_t)E * 4);
    // buckets (12.85 MB) dead after fill_bucket; y (12.8 MB) first written by
    // gemm L1 afterwards (stream-ordered) -> alias the same region.
    char*     bucket_mem = carve((size_t)NB * CAP * 8);
    int2*     buckets    = (int2*)bucket_mem;
    void*     y          = (void*)bucket_mem;
    uint16_t* ahi        = (uint16_t*)carve((size_t)n * 128 * 2);
    uint16_t* alo        = (uint16_t*)carve((size_t)n * 128 * 2);
    uint16_t* w1h        = (uint16_t*)carve(128 * 128 * 2);
    uint16_t* w1l        = (uint16_t*)carve(128 * 128 * 2);
    uint16_t* w2h        = (uint16_t*)carve(128 * 128 * 2);
    uint16_t* w2l        = (uint16_t*)carve(128 * 128 * 2);
    uint16_t* w3h        = (uint16_t*)carve(128 * 64 * 2);
    uint16_t* w3l        = (uint16_t*)carve(128 * 64 * 2);

    const int tpb = 256;
    int sb = (E + CHUNK - 1) / CHUNK;  // 391 scatter blocks

    // ---- CSR + norm build: bucket scatter + per-bucket local CSR ----
    init_cursors_kernel<<<1, 64, 0, stream>>>(bucket_cur);
    scatter_kernel<<<sb, tpb, 0, stream>>>(ei, bucket_cur, buckets, E);
    csr_local_kernel<<<NB, 512, 0, stream>>>(buckets, bucket_cur, row_ptr, bsum, dinv, n);
    scan_totals_kernel<<<1, 64, 0, stream>>>(bsum, boff, row_ptr, NB, n);
    fill_bucket_kernel<<<NB, 512, 0, stream>>>(buckets, bucket_cur, row_ptr, boff, col, n);
    w_split_all<<<160, tpb, 0, stream>>>(W1, W2, W3, w1h, w1l, w2h, w2l, w3h, w3l);

    int gb = 782;
    int ab = (n + 3) / 4;

    // ---- layer 1 (fp32 x, in-register split) ----
    gemm_mfma<128, true, true><<<gb, 256, 0, stream>>>(x, nullptr, w1h, w1l, dinv, y, n);
    aggregate_kernel<128, true, 1><<<ab, 256, 0, stream>>>(y, row_ptr, col, dinv, b1, ahi, alo, n);
    // ---- layer 2 ----
    gemm_mfma<128, true, false><<<gb, 256, 0, stream>>>(ahi, alo, w2h, w2l, dinv, y, n);
    aggregate_kernel<128, true, 1><<<ab, 256, 0, stream>>>(y, row_ptr, col, dinv, b2, ahi, alo, n);
    // ---- layer 3 (64 ch, bf16 y, no relu) ----
    gemm_mfma<64, true, false><<<gb, 256, 0, stream>>>(ahi, alo, w3h, w3l, dinv, y, n);
    aggregate_kernel<64, false, 0><<<ab, 256, 0, stream>>>(y, row_ptr, col, dinv, b3, d_out, nullptr, n);
}

// Round 7
// 248.417 us; speedup vs baseline: 3.0133x; 1.1399x over previous
//
#include <hip/hip_runtime.h>
#include <cstdint>

#define CAP 32768    // slots per bucket (expected fill ~16.3k)
#define CHUNK 2048   // edges per scatter block

typedef __attribute__((ext_vector_type(8))) short bf8_t;   // 8 bf16 = 4 VGPRs
typedef __attribute__((ext_vector_type(4))) float f4_t;

// ---------------------------------------------------------------------------
// bf16 helpers (RNE)
// ---------------------------------------------------------------------------
__device__ __forceinline__ uint32_t f_to_bf(float f) {
    union { float f; uint32_t u; } v; v.f = f;
    uint32_t u = v.u;
    return (u + 0x7fffu + ((u >> 16) & 1u)) >> 16;
}
__device__ __forceinline__ float bf_to_f(uint32_t h) {
    union { uint32_t u; float f; } v; v.u = h << 16; return v.f;
}
__device__ __forceinline__ float2 bf2_to_f2(uint32_t u) {
    union { uint32_t u; float f; } a, b;
    a.u = u << 16; b.u = u & 0xffff0000u;
    float2 r; r.x = a.f; r.y = b.f; return r;
}

// ---------------------------------------------------------------------------
// int64-vs-int32 edge layout detection (reference uses int64).
// ---------------------------------------------------------------------------
__device__ __forceinline__ int detect64(const int* __restrict__ e32) {
    return (e32[1] | e32[3] | e32[5] | e32[7]) == 0;
}
__device__ __forceinline__ int edge_at(const void* edges, int is64, int idx) {
    if (is64) return (int)((const long long*)edges)[idx];
    return ((const int*)edges)[idx];
}

// ---------------------------------------------------------------------------
// Prep: split all three W into MFMA B-frag hi/lo order + init bucket cursors.
// Grid = 161 blocks x 256 (blocks 0..159: 40960 w elements; block 160: cursors).
// ---------------------------------------------------------------------------
__global__ __launch_bounds__(256) void prep_kernel(
    const float* __restrict__ W1, const float* __restrict__ W2,
    const float* __restrict__ W3,
    uint16_t* w1h, uint16_t* w1l, uint16_t* w2h, uint16_t* w2l,
    uint16_t* w3h, uint16_t* w3l, int* __restrict__ bucket_cur) {
    if (blockIdx.x == 160) {
        if (threadIdx.x < 64) bucket_cur[threadIdx.x] = threadIdx.x * CAP;
        return;
    }
    int idx = blockIdx.x * 256 + threadIdx.x;
    const float* W; uint16_t* oh; uint16_t* ol; int FOUT; int e;
    if (idx < 16384)      { W = W1; oh = w1h; ol = w1l; FOUT = 128; e = idx; }
    else if (idx < 32768) { W = W2; oh = w2h; ol = w2l; FOUT = 128; e = idx - 16384; }
    else                  { W = W3; oh = w3h; ol = w3l; FOUT = 64;  e = idx - 32768; }
    int j = e & 7;
    int lane = (e >> 3) & 63;
    int rem = e >> 9;
    int NT = FOUT >> 4;
    int nt = rem % NT, kc = rem / NT;
    int k = kc * 32 + ((lane >> 4) << 3) + j;
    int c = nt * 16 + (lane & 15);
    float v = W[(size_t)k * FOUT + c];
    uint32_t h = f_to_bf(v);
    uint32_t l = f_to_bf(v - bf_to_f(h));
    oh[e] = (uint16_t)h;
    ol[e] = (uint16_t)l;
}

// ---------------------------------------------------------------------------
// Shared GEMM body: Y[i][:] = (A[i][:] @ W), bf16 out (unscaled).
// FOUT=128, NTW=2; A fp32 (in-register hi/lo split). Used by K1's gemm branch.
// ---------------------------------------------------------------------------
__device__ __forceinline__ void gemm1_body(
    const float* __restrict__ A, const uint16_t* __restrict__ Wfhi,
    const uint16_t* __restrict__ Wflo, uint16_t* __restrict__ Yout,
    int n, int cp, int tile0, int tstride, int lane) {
    constexpr int NT = 8, NTW = 2;
    int ntiles = (n + 15) >> 4;
    bf8_t wh[NTW][4], wl[NTW][4];
#pragma unroll
    for (int t = 0; t < NTW; t++) {
        int nt = cp * NTW + t;
#pragma unroll
        for (int kc = 0; kc < 4; kc++) {
            size_t b = ((size_t)(kc * NT + nt) * 64 + lane) * 8;
            wh[t][kc] = *(const bf8_t*)&Wfhi[b];
            wl[t][kc] = *(const bf8_t*)&Wflo[b];
        }
    }
    int row_in = lane & 15;
    int koff = (lane >> 4) << 3;
    int colb = lane & 15;
    int rq = (lane >> 4) << 2;
    for (int tile = tile0; tile < ntiles; tile += tstride) {
        int R = tile << 4;
        int arow = R + row_in; if (arow >= n) arow = n - 1;
        const float* ap = A + (size_t)arow * 128 + koff;
        bf8_t ah[4], al[4];
#pragma unroll
        for (int kc = 0; kc < 4; kc++) {
            float4 pv = *(const float4*)(ap + kc * 32);
            float4 qv = *(const float4*)(ap + kc * 32 + 4);
            float vv[8] = {pv.x, pv.y, pv.z, pv.w, qv.x, qv.y, qv.z, qv.w};
#pragma unroll
            for (int j = 0; j < 8; j++) {
                uint32_t h = f_to_bf(vv[j]);
                ah[kc][j] = (short)h;
                al[kc][j] = (short)f_to_bf(vv[j] - bf_to_f(h));
            }
        }
        f4_t acc[NTW];
#pragma unroll
        for (int t = 0; t < NTW; t++) acc[t] = (f4_t){0.f, 0.f, 0.f, 0.f};
#pragma unroll
        for (int kc = 0; kc < 4; kc++) {
#pragma unroll
            for (int t = 0; t < NTW; t++) {
                acc[t] = __builtin_amdgcn_mfma_f32_16x16x32_bf16(ah[kc], wh[t][kc], acc[t], 0, 0, 0);
                acc[t] = __builtin_amdgcn_mfma_f32_16x16x32_bf16(ah[kc], wl[t][kc], acc[t], 0, 0, 0);
                acc[t] = __builtin_amdgcn_mfma_f32_16x16x32_bf16(al[kc], wh[t][kc], acc[t], 0, 0, 0);
            }
        }
#pragma unroll
        for (int t = 0; t < NTW; t++) {
            int c = (cp * NTW + t) * 16 + colb;
#pragma unroll
            for (int r = 0; r < 4; r++) {
                int row = R + rq + r;
                if (row < n)
                    Yout[(size_t)row * 128 + c] = (uint16_t)f_to_bf(acc[t][r]);
            }
        }
    }
}

// ---------------------------------------------------------------------------
// K1: blocks [0,sbcnt) scatter edges into dst buckets; blocks [sbcnt,..)
// compute y1' = x @ W1 (UNscaled; dinv not yet available -> applied at gather).
// ---------------------------------------------------------------------------
__global__ __launch_bounds__(256) void scatter_gemm1_kernel(
    const void* __restrict__ ei, int* __restrict__ bucket_cur,
    int2* __restrict__ buckets, int E, int sbcnt,
    const float* __restrict__ x, const uint16_t* __restrict__ w1h,
    const uint16_t* __restrict__ w1l, uint16_t* __restrict__ y1, int n) {
    int tid = threadIdx.x;
    if ((int)blockIdx.x < sbcnt) {
        __shared__ int cnt[64];
        int base = blockIdx.x * CHUNK;
        int is64 = detect64((const int*)ei);
        if (tid < 64) cnt[tid] = 0;
        __syncthreads();
        int dloc[8];
#pragma unroll
        for (int it = 0; it < 8; it++) {
            int i = base + it * 256 + tid;
            int d = (i < E) ? edge_at(ei, is64, E + i) : -1;
            dloc[it] = d;
            if (d >= 0) atomicAdd(&cnt[d >> 10], 1);
        }
        __syncthreads();
        if (tid < 64) {
            int v = cnt[tid];
            cnt[tid] = atomicAdd(&bucket_cur[tid], v);
        }
        __syncthreads();
#pragma unroll
        for (int it = 0; it < 8; it++) {
            int i = base + it * 256 + tid;
            if (dloc[it] >= 0) {
                int s = edge_at(ei, is64, i);
                int p = atomicAdd(&cnt[dloc[it] >> 10], 1);
                buckets[p] = make_int2(s, dloc[it]);
            }
        }
    } else {
        int lane = tid & 63, wid = tid >> 6;
        gemm1_body(x, w1h, w1l, y1, n, wid, blockIdx.x - sbcnt,
                   gridDim.x - sbcnt, lane);
    }
}

// ---------------------------------------------------------------------------
// Per-bucket CSR phase 1: histogram, dinv, block-local exclusive scan.
// ---------------------------------------------------------------------------
__global__ __launch_bounds__(512) void csr_local_kernel(
    const int2* __restrict__ buckets, const int* __restrict__ bucket_cur,
    int* __restrict__ row_ptr, int* __restrict__ bsum, float* __restrict__ dinv, int n) {
    __shared__ int cnt[1024];
    __shared__ int sb[1024];
    int b = blockIdx.x, tid = threadIdx.x;
    int base = b << 10;
    int lim = min(1024, n - base);
    if (lim <= 0) { if (tid == 0) bsum[b] = 0; return; }
    int ecnt = bucket_cur[b] - b * CAP;
    const int2* ebase = buckets + (size_t)b * CAP;
    for (int i = tid; i < 1024; i += 512) cnt[i] = 0;
    __syncthreads();
    for (int i = tid; i < ecnt; i += 512)
        atomicAdd(&cnt[ebase[i].y - base], 1);
    __syncthreads();
    for (int i = tid; i < lim; i += 512)
        dinv[base + i] = rsqrtf((float)(cnt[i] + 1));  // +1 = self-loop
    __syncthreads();
    int* a = cnt; int* s = sb;
    for (int st = 1; st < 1024; st <<= 1) {
        for (int i = tid; i < 1024; i += 512)
            s[i] = a[i] + ((i >= st) ? a[i - st] : 0);
        __syncthreads();
        int* t = a; a = s; s = t;
    }
    for (int i = tid; i < lim; i += 512)
        row_ptr[base + i] = (i > 0) ? a[i - 1] : 0;
    if (tid == 0) bsum[b] = a[1023];
}

// Cross-bucket scan of totals -> boff; row_ptr[n] = grand total.
__global__ void scan_totals_kernel(const int* __restrict__ bsum, int* __restrict__ boff,
                                   int* __restrict__ row_ptr, int nb, int n) {
    int lane = threadIdx.x;
    int v = (lane < nb) ? bsum[lane] : 0;
    int incl = v;
#pragma unroll
    for (int off = 1; off < 64; off <<= 1) {
        int t = __shfl_up(incl, off);
        if (lane >= off) incl += t;
    }
    if (lane < nb) boff[lane] = incl - v;
    if (lane == 63) row_ptr[n] = incl;
}

// ---------------------------------------------------------------------------
// Per-bucket CSR phase 2: finalize row_ptr, LDS cursors, fill col.
// ---------------------------------------------------------------------------
__global__ __launch_bounds__(512) void fill_bucket_kernel(
    const int2* __restrict__ buckets, const int* __restrict__ bucket_cur,
    int* __restrict__ row_ptr, const int* __restrict__ boff,
    int* __restrict__ col, int n) {
    __shared__ int cur[1024];
    int b = blockIdx.x, tid = threadIdx.x;
    int base = b << 10;
    int lim = min(1024, n - base);
    if (lim <= 0) return;
    int ecnt = bucket_cur[b] - b * CAP;
    const int2* ebase = buckets + (size_t)b * CAP;
    int bo = boff[b];
    for (int i = tid; i < lim; i += 512) {
        int v = row_ptr[base + i] + bo;
        row_ptr[base + i] = v;
        cur[i] = v;
    }
    __syncthreads();
    for (int i = tid; i < ecnt; i += 512) {
        int2 e = ebase[i];
        int p = atomicAdd(&cur[e.y - base], 1);
        col[p] = e.x;
    }
}

// ---------------------------------------------------------------------------
// Fused aggregate + next-layer GEMM. Block = 4 waves = 16 nodes.
// Phase A: wave w aggregates nodes base+w*4+q (q=0..3): lane holds 2 channels;
//   h = relu(agg * dinv + bias), stored to LDS as hi/lo bf16 (row pad +8).
// Phase B: 16-row MFMA tile for next layer: Yout = (h @ W) * dinv (bf16).
// SRC_SCALE: Yin is unscaled (layer 1) -> multiply each gathered row by
// dinv[src] (self term uses dinv[node]).
// ---------------------------------------------------------------------------
template <int FOUT, bool SRC_SCALE>
__global__ __launch_bounds__(256) void agg_gemm_kernel(
    const uint16_t* __restrict__ Yin, const int* __restrict__ row_ptr,
    const int* __restrict__ col, const float* __restrict__ dinv,
    const float* __restrict__ bias,
    const uint16_t* __restrict__ Wfhi, const uint16_t* __restrict__ Wflo,
    uint16_t* __restrict__ Yout, int n) {
    constexpr int LDW = 136;  // uint16 row stride (128 + 8 pad)
    __shared__ uint16_t hs[16 * LDW];
    __shared__ uint16_t ls[16 * LDW];
    int tid = threadIdx.x, wid = tid >> 6, lane = tid & 63;
    int base = blockIdx.x * 16;

    auto lr = [&](int node) -> float2 {
        uint32_t u = ((const uint32_t*)Yin)[(size_t)node * 64 + lane];
        return bf2_to_f2(u);
    };

    for (int q = 0; q < 4; q++) {
        int r = wid * 4 + q, node = base + r;
        uint32_t ph = 0, pl = 0;
        if (node < n) {
            float di = dinv[node];
            float2 a0, a1, a2, a3;
            {
                float2 s = lr(node);
                float sc = SRC_SCALE ? di : 1.f;
                a0.x = s.x * sc; a0.y = s.y * sc;
            }
            a1 = (float2){0.f, 0.f}; a2 = (float2){0.f, 0.f}; a3 = (float2){0.f, 0.f};
            int start = row_ptr[node], end = row_ptr[node + 1];
            for (int b = start; b < end; b += 64) {
                int cnt = min(64, end - b);
                int sv = (b + lane < end) ? col[b + lane] : 0;
                int j = 0;
                for (; j + 4 <= cnt; j += 4) {
                    int s0 = __shfl(sv, j),     s1 = __shfl(sv, j + 1);
                    int s2 = __shfl(sv, j + 2), s3 = __shfl(sv, j + 3);
                    float d0 = 1.f, d1 = 1.f, d2 = 1.f, d3 = 1.f;
                    if (SRC_SCALE) { d0 = dinv[s0]; d1 = dinv[s1]; d2 = dinv[s2]; d3 = dinv[s3]; }
                    float2 v0 = lr(s0), v1 = lr(s1), v2 = lr(s2), v3 = lr(s3);
                    a0.x += v0.x * d0; a0.y += v0.y * d0;
                    a1.x += v1.x * d1; a1.y += v1.y * d1;
                    a2.x += v2.x * d2; a2.y += v2.y * d2;
                    a3.x += v3.x * d3; a3.y += v3.y * d3;
                }
                for (; j < cnt; j++) {
                    int s = __shfl(sv, j);
                    float d0 = SRC_SCALE ? dinv[s] : 1.f;
                    float2 v = lr(s);
                    a0.x += v.x * d0; a0.y += v.y * d0;
                }
            }
            float sx = (a0.x + a1.x) + (a2.x + a3.x);
            float sy = (a0.y + a1.y) + (a2.y + a3.y);
            float ox = fmaxf(sx * di + bias[2 * lane], 0.f);      // relu (layers 1,2)
            float oy = fmaxf(sy * di + bias[2 * lane + 1], 0.f);
            uint32_t h0 = f_to_bf(ox), h1 = f_to_bf(oy);
            uint32_t l0 = f_to_bf(ox - bf_to_f(h0)), l1 = f_to_bf(oy - bf_to_f(h1));
            ph = h0 | (h1 << 16); pl = l0 | (l1 << 16);
        }
        ((uint32_t*)(hs + r * LDW))[lane] = ph;
        ((uint32_t*)(ls + r * LDW))[lane] = pl;
    }
    __syncthreads();

    // ---- GEMM phase ----
    constexpr int NT = FOUT / 16;
    constexpr int NTW = NT / 4;   // 128 -> 2 col tiles/wave, 64 -> 1
    int cp = wid;
    bf8_t wh[NTW][4], wl[NTW][4];
#pragma unroll
    for (int t = 0; t < NTW; t++) {
        int nt = cp * NTW + t;
#pragma unroll
        for (int kc = 0; kc < 4; kc++) {
            size_t b = ((size_t)(kc * NT + nt) * 64 + lane) * 8;
            wh[t][kc] = *(const bf8_t*)&Wfhi[b];
            wl[t][kc] = *(const bf8_t*)&Wflo[b];
        }
    }
    int koff = (lane >> 4) << 3;
    int colb = lane & 15;
    int rq = (lane >> 4) << 2;
    bf8_t ah[4], al[4];
#pragma unroll
    for (int kc = 0; kc < 4; kc++) {
        ah[kc] = *(const bf8_t*)(hs + (lane & 15) * LDW + koff + kc * 32);
        al[kc] = *(const bf8_t*)(ls + (lane & 15) * LDW + koff + kc * 32);
    }
    f4_t acc[NTW];
#pragma unroll
    for (int t = 0; t < NTW; t++) acc[t] = (f4_t){0.f, 0.f, 0.f, 0.f};
#pragma unroll
    for (int kc = 0; kc < 4; kc++) {
#pragma unroll
        for (int t = 0; t < NTW; t++) {
            acc[t] = __builtin_amdgcn_mfma_f32_16x16x32_bf16(ah[kc], wh[t][kc], acc[t], 0, 0, 0);
            acc[t] = __builtin_amdgcn_mfma_f32_16x16x32_bf16(ah[kc], wl[t][kc], acc[t], 0, 0, 0);
            acc[t] = __builtin_amdgcn_mfma_f32_16x16x32_bf16(al[kc], wh[t][kc], acc[t], 0, 0, 0);
        }
    }
#pragma unroll
    for (int t = 0; t < NTW; t++) {
        int c = (cp * NTW + t) * 16 + colb;
#pragma unroll
        for (int r = 0; r < 4; r++) {
            int row = base + rq + r;
            if (row < n) {
                float v = acc[t][r] * dinv[row];
                Yout[(size_t)row * FOUT + c] = (uint16_t)f_to_bf(v);
            }
        }
    }
}

// ---------------------------------------------------------------------------
// Final aggregate (layer 3): 64 ch, fp32 out, no relu. One wave per node.
// ---------------------------------------------------------------------------
__global__ __launch_bounds__(256) void agg_final_kernel(
    const uint16_t* __restrict__ Y, const int* __restrict__ row_ptr,
    const int* __restrict__ col, const float* __restrict__ dinv,
    const float* __restrict__ bias, float* __restrict__ out, int n) {
    int w = blockIdx.x * 4 + (threadIdx.x >> 6);
    int lane = threadIdx.x & 63;
    if (w >= n) return;
    auto lr = [&](int node) -> float {
        return bf_to_f(Y[(size_t)node * 64 + lane]);
    };
    float a0 = lr(w), a1 = 0.f, a2 = 0.f, a3 = 0.f;
    int start = row_ptr[w], end = row_ptr[w + 1];
    for (int b = start; b < end; b += 64) {
        int cnt = min(64, end - b);
        int sv = (b + lane < end) ? col[b + lane] : 0;
        int j = 0;
        for (; j + 4 <= cnt; j += 4) {
            int s0 = __shfl(sv, j),     s1 = __shfl(sv, j + 1);
            int s2 = __shfl(sv, j + 2), s3 = __shfl(sv, j + 3);
            a0 += lr(s0); a1 += lr(s1); a2 += lr(s2); a3 += lr(s3);
        }
        for (; j < cnt; j++) a0 += lr(__shfl(sv, j));
    }
    float ox = ((a0 + a1) + (a2 + a3)) * dinv[w] + bias[lane];
    out[(size_t)w * 64 + lane] = ox;
}

extern "C" void kernel_launch(void* const* d_in, const int* in_sizes, int n_in,
                              void* d_out, int out_size, void* d_ws, size_t ws_size,
                              hipStream_t stream) {
    const float* x  = (const float*)d_in[0];
    const void*  ei = d_in[1];
    const float* W1 = (const float*)d_in[2];
    const float* b1 = (const float*)d_in[3];
    const float* W2 = (const float*)d_in[4];
    const float* b2 = (const float*)d_in[5];
    const float* W3 = (const float*)d_in[6];
    const float* b3 = (const float*)d_in[7];
    int n = in_sizes[0] / 128;     // 50000
    int E = in_sizes[1] / 2;       // 800000
    int nbuck = (n + 1023) >> 10;  // 49 (<= 64)

    char* p = (char*)d_ws;
    auto carve = [&](size_t bytes) {
        char* r = p;
        p += (bytes + 255) & ~(size_t)255;
        return r;
    };
    float*    dinv       = (float*)carve((size_t)n * 4);
    int*      row_ptr    = (int*)carve((size_t)(n + 1) * 4);
    int*      bsum       = (int*)carve(64 * 4);
    int*      boff       = (int*)carve(64 * 4);
    int*      bucket_cur = (int*)carve(64 * 4);
    int*      col        = (int*)carve((size_t)E * 4);
    int2*     buckets    = (int2*)carve((size_t)64 * CAP * 8);
    uint16_t* y1         = (uint16_t*)carve((size_t)n * 128 * 2);
    uint16_t* y2         = (uint16_t*)carve((size_t)n * 128 * 2);
    uint16_t* y3         = (uint16_t*)carve((size_t)n * 64 * 2);
    uint16_t* w1h        = (uint16_t*)carve(128 * 128 * 2);
    uint16_t* w1l        = (uint16_t*)carve(128 * 128 * 2);
    uint16_t* w2h        = (uint16_t*)carve(128 * 128 * 2);
    uint16_t* w2l        = (uint16_t*)carve(128 * 128 * 2);
    uint16_t* w3h        = (uint16_t*)carve(128 * 64 * 2);
    uint16_t* w3l        = (uint16_t*)carve(128 * 64 * 2);

    int sbcnt = (E + CHUNK - 1) / CHUNK;   // 391 scatter blocks
    int fb = (n + 15) / 16;                // 3125 fused blocks

    // K0: W splits + bucket cursor init
    prep_kernel<<<161, 256, 0, stream>>>(W1, W2, W3, w1h, w1l, w2h, w2l,
                                         w3h, w3l, bucket_cur);
    // K1: edge scatter || gemm1 (y1' = x@W1, unscaled)
    scatter_gemm1_kernel<<<sbcnt + 782, 256, 0, stream>>>(
        ei, bucket_cur, buckets, E, sbcnt, x, w1h, w1l, y1, n);
    // K2-4: per-bucket CSR
    csr_local_kernel<<<nbuck, 512, 0, stream>>>(buckets, bucket_cur, row_ptr, bsum, dinv, n);
    scan_totals_kernel<<<1, 64, 0, stream>>>(bsum, boff, row_ptr, nbuck, n);
    fill_bucket_kernel<<<nbuck, 512, 0, stream>>>(buckets, bucket_cur, row_ptr, boff, col, n);
    // K5: agg1 (src-scaled) + gemm2 -> y2 (scaled)
    agg_gemm_kernel<128, true><<<fb, 256, 0, stream>>>(
        y1, row_ptr, col, dinv, b1, w2h, w2l, y2, n);
    // K6: agg2 + gemm3 -> y3 (scaled)
    agg_gemm_kernel<64, false><<<fb, 256, 0, stream>>>(
        y2, row_ptr, col, dinv, b2, w3h, w3l, y3, n);
    // K7: final aggregate -> d_out
    agg_final_kernel<<<(n + 3) / 4, 256, 0, stream>>>(
        y3, row_ptr, col, dinv, b3, (float*)d_out, n);
}

// Round 8
// 242.217 us; speedup vs baseline: 3.0904x; 1.0256x over previous
//
#include <hip/hip_runtime.h>
#include <cstdint>

#define CAP 32768    // slots per bucket (expected fill ~16.3k)
#define CHUNK 2048   // edges per scatter block

typedef __attribute__((ext_vector_type(8))) short bf8_t;   // 8 bf16 = 4 VGPRs
typedef __attribute__((ext_vector_type(4))) float f4_t;

// ---------------------------------------------------------------------------
// bf16 helpers (RNE)
// ---------------------------------------------------------------------------
__device__ __forceinline__ uint32_t f_to_bf(float f) {
    union { float f; uint32_t u; } v; v.f = f;
    uint32_t u = v.u;
    return (u + 0x7fffu + ((u >> 16) & 1u)) >> 16;
}
__device__ __forceinline__ float bf_to_f(uint32_t h) {
    union { uint32_t u; float f; } v; v.u = h << 16; return v.f;
}
__device__ __forceinline__ float2 bf2_to_f2(uint32_t u) {
    union { uint32_t u; float f; } a, b;
    a.u = u << 16; b.u = u & 0xffff0000u;
    float2 r; r.x = a.f; r.y = b.f; return r;
}
// acc[0..7] += (8 bf16 in u) * d
__device__ __forceinline__ void fma8(float* acc, uint4 u, float d) {
    float2 p0 = bf2_to_f2(u.x), p1 = bf2_to_f2(u.y);
    float2 p2 = bf2_to_f2(u.z), p3 = bf2_to_f2(u.w);
    acc[0] += p0.x * d; acc[1] += p0.y * d;
    acc[2] += p1.x * d; acc[3] += p1.y * d;
    acc[4] += p2.x * d; acc[5] += p2.y * d;
    acc[6] += p3.x * d; acc[7] += p3.y * d;
}

// ---------------------------------------------------------------------------
// int64-vs-int32 edge layout detection (reference uses int64).
// ---------------------------------------------------------------------------
__device__ __forceinline__ int detect64(const int* __restrict__ e32) {
    return (e32[1] | e32[3] | e32[5] | e32[7]) == 0;
}
__device__ __forceinline__ int edge_at(const void* edges, int is64, int idx) {
    if (is64) return (int)((const long long*)edges)[idx];
    return ((const int*)edges)[idx];
}

// ---------------------------------------------------------------------------
// Prep: split all three W into MFMA B-frag hi/lo order + init bucket cursors.
// ---------------------------------------------------------------------------
__global__ __launch_bounds__(256) void prep_kernel(
    const float* __restrict__ W1, const float* __restrict__ W2,
    const float* __restrict__ W3,
    uint16_t* w1h, uint16_t* w1l, uint16_t* w2h, uint16_t* w2l,
    uint16_t* w3h, uint16_t* w3l, int* __restrict__ bucket_cur) {
    if (blockIdx.x == 160) {
        if (threadIdx.x < 64) bucket_cur[threadIdx.x] = threadIdx.x * CAP;
        return;
    }
    int idx = blockIdx.x * 256 + threadIdx.x;
    const float* W; uint16_t* oh; uint16_t* ol; int FOUT; int e;
    if (idx < 16384)      { W = W1; oh = w1h; ol = w1l; FOUT = 128; e = idx; }
    else if (idx < 32768) { W = W2; oh = w2h; ol = w2l; FOUT = 128; e = idx - 16384; }
    else                  { W = W3; oh = w3h; ol = w3l; FOUT = 64;  e = idx - 32768; }
    int j = e & 7;
    int lane = (e >> 3) & 63;
    int rem = e >> 9;
    int NT = FOUT >> 4;
    int nt = rem % NT, kc = rem / NT;
    int k = kc * 32 + ((lane >> 4) << 3) + j;
    int c = nt * 16 + (lane & 15);
    float v = W[(size_t)k * FOUT + c];
    uint32_t h = f_to_bf(v);
    uint32_t l = f_to_bf(v - bf_to_f(h));
    oh[e] = (uint16_t)h;
    ol[e] = (uint16_t)l;
}

// ---------------------------------------------------------------------------
// GEMM1 body: Y[i][:] = A[i][:] @ W (UNscaled), bf16 out. FOUT=128, K=128.
// ---------------------------------------------------------------------------
__device__ __forceinline__ void gemm1_body(
    const float* __restrict__ A, const uint16_t* __restrict__ Wfhi,
    const uint16_t* __restrict__ Wflo, uint16_t* __restrict__ Yout,
    int n, int cp, int tile0, int tstride, int lane) {
    constexpr int NT = 8, NTW = 2;
    int ntiles = (n + 15) >> 4;
    bf8_t wh[NTW][4], wl[NTW][4];
#pragma unroll
    for (int t = 0; t < NTW; t++) {
        int nt = cp * NTW + t;
#pragma unroll
        for (int kc = 0; kc < 4; kc++) {
            size_t b = ((size_t)(kc * NT + nt) * 64 + lane) * 8;
            wh[t][kc] = *(const bf8_t*)&Wfhi[b];
            wl[t][kc] = *(const bf8_t*)&Wflo[b];
        }
    }
    int row_in = lane & 15;
    int koff = (lane >> 4) << 3;
    int colb = lane & 15;
    int rq = (lane >> 4) << 2;
    for (int tile = tile0; tile < ntiles; tile += tstride) {
        int R = tile << 4;
        int arow = R + row_in; if (arow >= n) arow = n - 1;
        const float* ap = A + (size_t)arow * 128 + koff;
        bf8_t ah[4], al[4];
#pragma unroll
        for (int kc = 0; kc < 4; kc++) {
            float4 pv = *(const float4*)(ap + kc * 32);
            float4 qv = *(const float4*)(ap + kc * 32 + 4);
            float vv[8] = {pv.x, pv.y, pv.z, pv.w, qv.x, qv.y, qv.z, qv.w};
#pragma unroll
            for (int j = 0; j < 8; j++) {
                uint32_t h = f_to_bf(vv[j]);
                ah[kc][j] = (short)h;
                al[kc][j] = (short)f_to_bf(vv[j] - bf_to_f(h));
            }
        }
        f4_t acc[NTW];
#pragma unroll
        for (int t = 0; t < NTW; t++) acc[t] = (f4_t){0.f, 0.f, 0.f, 0.f};
#pragma unroll
        for (int kc = 0; kc < 4; kc++) {
#pragma unroll
            for (int t = 0; t < NTW; t++) {
                acc[t] = __builtin_amdgcn_mfma_f32_16x16x32_bf16(ah[kc], wh[t][kc], acc[t], 0, 0, 0);
                acc[t] = __builtin_amdgcn_mfma_f32_16x16x32_bf16(ah[kc], wl[t][kc], acc[t], 0, 0, 0);
                acc[t] = __builtin_amdgcn_mfma_f32_16x16x32_bf16(al[kc], wh[t][kc], acc[t], 0, 0, 0);
            }
        }
#pragma unroll
        for (int t = 0; t < NTW; t++) {
            int c = (cp * NTW + t) * 16 + colb;
#pragma unroll
            for (int r = 0; r < 4; r++) {
                int row = R + rq + r;
                if (row < n)
                    Yout[(size_t)row * 128 + c] = (uint16_t)f_to_bf(acc[t][r]);
            }
        }
    }
}

// ---------------------------------------------------------------------------
// K1: blocks [0,sbcnt) scatter edges into dst buckets; rest run gemm1.
// ---------------------------------------------------------------------------
__global__ __launch_bounds__(256) void scatter_gemm1_kernel(
    const void* __restrict__ ei, int* __restrict__ bucket_cur,
    int2* __restrict__ buckets, int E, int sbcnt,
    const float* __restrict__ x, const uint16_t* __restrict__ w1h,
    const uint16_t* __restrict__ w1l, uint16_t* __restrict__ y1, int n) {
    int tid = threadIdx.x;
    if ((int)blockIdx.x < sbcnt) {
        __shared__ int cnt[64];
        int base = blockIdx.x * CHUNK;
        int is64 = detect64((const int*)ei);
        if (tid < 64) cnt[tid] = 0;
        __syncthreads();
        int dloc[8];
#pragma unroll
        for (int it = 0; it < 8; it++) {
            int i = base + it * 256 + tid;
            int d = (i < E) ? edge_at(ei, is64, E + i) : -1;
            dloc[it] = d;
            if (d >= 0) atomicAdd(&cnt[d >> 10], 1);
        }
        __syncthreads();
        if (tid < 64) {
            int v = cnt[tid];
            cnt[tid] = atomicAdd(&bucket_cur[tid], v);
        }
        __syncthreads();
#pragma unroll
        for (int it = 0; it < 8; it++) {
            int i = base + it * 256 + tid;
            if (dloc[it] >= 0) {
                int s = edge_at(ei, is64, i);
                int p = atomicAdd(&cnt[dloc[it] >> 10], 1);
                buckets[p] = make_int2(s, dloc[it]);
            }
        }
    } else {
        int lane = tid & 63, wid = tid >> 6;
        gemm1_body(x, w1h, w1l, y1, n, wid, blockIdx.x - sbcnt,
                   gridDim.x - sbcnt, lane);
    }
}

// ---------------------------------------------------------------------------
// Per-bucket CSR phase 1: histogram, dinv, block-local exclusive scan.
// ---------------------------------------------------------------------------
__global__ __launch_bounds__(512) void csr_local_kernel(
    const int2* __restrict__ buckets, const int* __restrict__ bucket_cur,
    int* __restrict__ row_ptr, int* __restrict__ bsum, float* __restrict__ dinv, int n) {
    __shared__ int cnt[1024];
    __shared__ int sb[1024];
    int b = blockIdx.x, tid = threadIdx.x;
    int base = b << 10;
    int lim = min(1024, n - base);
    if (lim <= 0) { if (tid == 0) bsum[b] = 0; return; }
    int ecnt = bucket_cur[b] - b * CAP;
    const int2* ebase = buckets + (size_t)b * CAP;
    for (int i = tid; i < 1024; i += 512) cnt[i] = 0;
    __syncthreads();
    for (int i = tid; i < ecnt; i += 512)
        atomicAdd(&cnt[ebase[i].y - base], 1);
    __syncthreads();
    for (int i = tid; i < lim; i += 512)
        dinv[base + i] = rsqrtf((float)(cnt[i] + 1));  // +1 = self-loop
    __syncthreads();
    int* a = cnt; int* s = sb;
    for (int st = 1; st < 1024; st <<= 1) {
        for (int i = tid; i < 1024; i += 512)
            s[i] = a[i] + ((i >= st) ? a[i - st] : 0);
        __syncthreads();
        int* t = a; a = s; s = t;
    }
    for (int i = tid; i < lim; i += 512)
        row_ptr[base + i] = (i > 0) ? a[i - 1] : 0;
    if (tid == 0) bsum[b] = a[1023];
}

// ---------------------------------------------------------------------------
// Per-bucket CSR phase 2 (scan_totals folded in): wave0 scans bsum -> boff,
// finalize row_ptr, LDS cursors, fill col. Block nbuck-1 writes row_ptr[n].
// ---------------------------------------------------------------------------
__global__ __launch_bounds__(512) void fill_bucket_kernel(
    const int2* __restrict__ buckets, const int* __restrict__ bucket_cur,
    int* __restrict__ row_ptr, const int* __restrict__ bsum,
    int* __restrict__ col, int n, int nbuck) {
    __shared__ int cur[1024];
    __shared__ int s_bo;
    int b = blockIdx.x, tid = threadIdx.x;
    int base = b << 10;
    int lim = min(1024, n - base);
    if (lim <= 0) return;
    if (tid < 64) {
        int lane = tid;
        int v = (lane < nbuck) ? bsum[lane] : 0;
        int incl = v;
#pragma unroll
        for (int off = 1; off < 64; off <<= 1) {
            int t = __shfl_up(incl, off);
            if (lane >= off) incl += t;
        }
        int tot = __shfl(incl, nbuck - 1);
        int bo = (b > 0) ? __shfl(incl, b - 1) : 0;
        if (lane == 0) {
            s_bo = bo;
            if (b == nbuck - 1) row_ptr[n] = tot;
        }
    }
    __syncthreads();
    int ecnt = bucket_cur[b] - b * CAP;
    const int2* ebase = buckets + (size_t)b * CAP;
    int bo = s_bo;
    for (int i = tid; i < lim; i += 512) {
        int v = row_ptr[base + i] + bo;
        row_ptr[base + i] = v;
        cur[i] = v;
    }
    __syncthreads();
    for (int i = tid; i < ecnt; i += 512) {
        int2 e = ebase[i];
        int p = atomicAdd(&cur[e.y - base], 1);
        col[p] = e.x;
    }
}

// ---------------------------------------------------------------------------
// Fused aggregate + next-layer GEMM. Block = 4 waves = 16 nodes.
// Agg phase (CH=128 input, 16B/lane gather): lane = (j=lane>>4 edge slot,
// g=lane&15 channel group of 8). One dwordx4 load fetches 4 edge rows/wave.
// Butterfly (xor 16,32) reduces j; lanes j==0 write h hi/lo to LDS.
// GEMM phase: 16-row MFMA tile; Yout = (h @ W) * dinv, bf16.
// SRC_SCALE: gathered rows scaled by dinv[src] (layer 1, y1 unscaled).
// ---------------------------------------------------------------------------
template <int FOUT, bool SRC_SCALE>
__global__ __launch_bounds__(256) void agg_gemm_kernel(
    const uint16_t* __restrict__ Yin, const int* __restrict__ row_ptr,
    const int* __restrict__ col, const float* __restrict__ dinv,
    const float* __restrict__ bias,
    const uint16_t* __restrict__ Wfhi, const uint16_t* __restrict__ Wflo,
    uint16_t* __restrict__ Yout, int n) {
    __shared__ uint4 hs4[16 * 17];   // 16 rows x 136 uint16 (pad 8)
    __shared__ uint4 ls4[16 * 17];
    int tid = threadIdx.x, wid = tid >> 6, lane = tid & 63;
    int base = blockIdx.x * 16;
    int g = lane & 15, j = lane >> 4;
    const uint4* Y4 = (const uint4*)Yin;

    // bias channels for my group (invariant over q)
    float4 bb0 = *(const float4*)&bias[g * 8];
    float4 bb1 = *(const float4*)&bias[g * 8 + 4];
    float bb[8] = {bb0.x, bb0.y, bb0.z, bb0.w, bb1.x, bb1.y, bb1.z, bb1.w};

    for (int q = 0; q < 4; q++) {
        int r = wid * 4 + q, node = base + r;
        uint4 ph = (uint4){0, 0, 0, 0}, pl = (uint4){0, 0, 0, 0};
        if (node < n) {
            float di = dinv[node];
            float aA[8] = {}, aB[8] = {};
            // self term: only j==0 lanes contribute
            {
                float sd = (j == 0) ? (SRC_SCALE ? di : 1.f) : 0.f;
                uint4 su = Y4[(size_t)node * 16 + g];
                fma8(aA, su, sd);
            }
            int start = row_ptr[node], end = row_ptr[node + 1];
            for (int b = start; b < end; b += 64) {
                int cnt = min(64, end - b);
                int sv = (b + lane < end) ? col[b + lane] : 0;
                for (int k = 0; k < cnt; k += 8) {
                    int iA = k + j, iB = k + 4 + j;
                    int sA = __shfl(sv, iA & 63);
                    int sB = __shfl(sv, iB & 63);
                    float dA = (iA < cnt) ? (SRC_SCALE ? dinv[sA] : 1.f) : 0.f;
                    float dB = (iB < cnt) ? (SRC_SCALE ? dinv[sB] : 1.f) : 0.f;
                    uint4 uA = Y4[(size_t)sA * 16 + g];
                    uint4 uB = Y4[(size_t)sB * 16 + g];
                    fma8(aA, uA, dA);
                    fma8(aB, uB, dB);
                }
            }
            float o[8];
#pragma unroll
            for (int t = 0; t < 8; t++) o[t] = aA[t] + aB[t];
#pragma unroll
            for (int t = 0; t < 8; t++) o[t] += __shfl_xor(o[t], 16);
#pragma unroll
            for (int t = 0; t < 8; t++) o[t] += __shfl_xor(o[t], 32);
            uint32_t hh[8];
#pragma unroll
            for (int t = 0; t < 8; t++) {
                o[t] = fmaxf(o[t] * di + bb[t], 0.f);   // relu (layers 1,2)
                hh[t] = f_to_bf(o[t]);
            }
            ph = (uint4){hh[0] | (hh[1] << 16), hh[2] | (hh[3] << 16),
                         hh[4] | (hh[5] << 16), hh[6] | (hh[7] << 16)};
            uint32_t ll[8];
#pragma unroll
            for (int t = 0; t < 8; t++) ll[t] = f_to_bf(o[t] - bf_to_f(hh[t]));
            pl = (uint4){ll[0] | (ll[1] << 16), ll[2] | (ll[3] << 16),
                         ll[4] | (ll[5] << 16), ll[6] | (ll[7] << 16)};
        }
        if (j == 0) {
            hs4[r * 17 + g] = ph;
            ls4[r * 17 + g] = pl;
        }
    }
    __syncthreads();

    // ---- GEMM phase ----
    const uint16_t* hs = (const uint16_t*)hs4;
    const uint16_t* ls = (const uint16_t*)ls4;
    constexpr int NT = FOUT / 16;
    constexpr int NTW = NT / 4;   // 128 -> 2 col tiles/wave, 64 -> 1
    constexpr int LDW = 136;
    int cp = wid;
    bf8_t wh[NTW][4], wl[NTW][4];
#pragma unroll
    for (int t = 0; t < NTW; t++) {
        int nt = cp * NTW + t;
#pragma unroll
        for (int kc = 0; kc < 4; kc++) {
            size_t b = ((size_t)(kc * NT + nt) * 64 + lane) * 8;
            wh[t][kc] = *(const bf8_t*)&Wfhi[b];
            wl[t][kc] = *(const bf8_t*)&Wflo[b];
        }
    }
    int koff = (lane >> 4) << 3;
    int colb = lane & 15;
    int rq = (lane >> 4) << 2;
    bf8_t ah[4], al[4];
#pragma unroll
    for (int kc = 0; kc < 4; kc++) {
        ah[kc] = *(const bf8_t*)(hs + (lane & 15) * LDW + koff + kc * 32);
        al[kc] = *(const bf8_t*)(ls + (lane & 15) * LDW + koff + kc * 32);
    }
    f4_t acc[NTW];
#pragma unroll
    for (int t = 0; t < NTW; t++) acc[t] = (f4_t){0.f, 0.f, 0.f, 0.f};
#pragma unroll
    for (int kc = 0; kc < 4; kc++) {
#pragma unroll
        for (int t = 0; t < NTW; t++) {
            acc[t] = __builtin_amdgcn_mfma_f32_16x16x32_bf16(ah[kc], wh[t][kc], acc[t], 0, 0, 0);
            acc[t] = __builtin_amdgcn_mfma_f32_16x16x32_bf16(ah[kc], wl[t][kc], acc[t], 0, 0, 0);
            acc[t] = __builtin_amdgcn_mfma_f32_16x16x32_bf16(al[kc], wh[t][kc], acc[t], 0, 0, 0);
        }
    }
#pragma unroll
    for (int t = 0; t < NTW; t++) {
        int c = (cp * NTW + t) * 16 + colb;
#pragma unroll
        for (int r = 0; r < 4; r++) {
            int row = base + rq + r;
            if (row < n) {
                float v = acc[t][r] * dinv[row];
                Yout[(size_t)row * FOUT + c] = (uint16_t)f_to_bf(v);
            }
        }
    }
}

// ---------------------------------------------------------------------------
// Final aggregate (layer 3): 64 ch, fp32 out, no relu. One wave per node,
// 16B/lane gather: g=lane&7 (8 ch), j=lane>>3 (8 edge slots).
// ---------------------------------------------------------------------------
__global__ __launch_bounds__(256) void agg_final_kernel(
    const uint16_t* __restrict__ Y, const int* __restrict__ row_ptr,
    const int* __restrict__ col, const float* __restrict__ dinv,
    const float* __restrict__ bias, float* __restrict__ out, int n) {
    int w = blockIdx.x * 4 + (threadIdx.x >> 6);
    int lane = threadIdx.x & 63;
    if (w >= n) return;
    int g = lane & 7, j = lane >> 3;
    const uint4* Y4 = (const uint4*)Y;
    float4 bb0 = *(const float4*)&bias[g * 8];
    float4 bb1 = *(const float4*)&bias[g * 8 + 4];
    float bb[8] = {bb0.x, bb0.y, bb0.z, bb0.w, bb1.x, bb1.y, bb1.z, bb1.w};

    float aA[8] = {}, aB[8] = {};
    {
        uint4 su = Y4[(size_t)w * 8 + g];
        fma8(aA, su, (j == 0) ? 1.f : 0.f);
    }
    int start = row_ptr[w], end = row_ptr[w + 1];
    for (int b = start; b < end; b += 64) {
        int cnt = min(64, end - b);
        int sv = (b + lane < end) ? col[b + lane] : 0;
        for (int k = 0; k < cnt; k += 16) {
            int iA = k + j, iB = k + 8 + j;
            int sA = __shfl(sv, iA & 63);
            int sB = __shfl(sv, iB & 63);
            float dA = (iA < cnt) ? 1.f : 0.f;
            float dB = (iB < cnt) ? 1.f : 0.f;
            uint4 uA = Y4[(size_t)sA * 8 + g];
            uint4 uB = Y4[(size_t)sB * 8 + g];
            fma8(aA, uA, dA);
            fma8(aB, uB, dB);
        }
    }
    float o[8];
#pragma unroll
    for (int t = 0; t < 8; t++) o[t] = aA[t] + aB[t];
#pragma unroll
    for (int t = 0; t < 8; t++) o[t] += __shfl_xor(o[t], 8);
#pragma unroll
    for (int t = 0; t < 8; t++) o[t] += __shfl_xor(o[t], 16);
#pragma unroll
    for (int t = 0; t < 8; t++) o[t] += __shfl_xor(o[t], 32);
    float di = dinv[w];
#pragma unroll
    for (int t = 0; t < 8; t++) o[t] = o[t] * di + bb[t];
    if (j == 0) {
        float4 o0 = {o[0], o[1], o[2], o[3]};
        float4 o1 = {o[4], o[5], o[6], o[7]};
        *(float4*)&out[(size_t)w * 64 + g * 8] = o0;
        *(float4*)&out[(size_t)w * 64 + g * 8 + 4] = o1;
    }
}

extern "C" void kernel_launch(void* const* d_in, const int* in_sizes, int n_in,
                              void* d_out, int out_size, void* d_ws, size_t ws_size,
                              hipStream_t stream) {
    const float* x  = (const float*)d_in[0];
    const void*  ei = d_in[1];
    const float* W1 = (const float*)d_in[2];
    const float* b1 = (const float*)d_in[3];
    const float* W2 = (const float*)d_in[4];
    const float* b2 = (const float*)d_in[5];
    const float* W3 = (const float*)d_in[6];
    const float* b3 = (const float*)d_in[7];
    int n = in_sizes[0] / 128;     // 50000
    int E = in_sizes[1] / 2;       // 800000
    int nbuck = (n + 1023) >> 10;  // 49 (<= 64)

    char* p = (char*)d_ws;
    auto carve = [&](size_t bytes) {
        char* r = p;
        p += (bytes + 255) & ~(size_t)255;
        return r;
    };
    float*    dinv       = (float*)carve((size_t)n * 4);
    int*      row_ptr    = (int*)carve((size_t)(n + 1) * 4);
    int*      bsum       = (int*)carve(64 * 4);
    int*      bucket_cur = (int*)carve(64 * 4);
    int*      col        = (int*)carve((size_t)E * 4);
    int2*     buckets    = (int2*)carve((size_t)64 * CAP * 8);
    uint16_t* y1         = (uint16_t*)carve((size_t)n * 128 * 2);
    uint16_t* y2         = (uint16_t*)carve((size_t)n * 128 * 2);
    uint16_t* y3         = (uint16_t*)carve((size_t)n * 64 * 2);
    uint16_t* w1h        = (uint16_t*)carve(128 * 128 * 2);
    uint16_t* w1l        = (uint16_t*)carve(128 * 128 * 2);
    uint16_t* w2h        = (uint16_t*)carve(128 * 128 * 2);
    uint16_t* w2l        = (uint16_t*)carve(128 * 128 * 2);
    uint16_t* w3h        = (uint16_t*)carve(128 * 64 * 2);
    uint16_t* w3l        = (uint16_t*)carve(128 * 64 * 2);

    int sbcnt = (E + CHUNK - 1) / CHUNK;   // 391 scatter blocks
    int fb = (n + 15) / 16;                // 3125 fused blocks

    // K0: W splits + bucket cursor init
    prep_kernel<<<161, 256, 0, stream>>>(W1, W2, W3, w1h, w1l, w2h, w2l,
                                         w3h, w3l, bucket_cur);
    // K1: edge scatter || gemm1 (y1' = x@W1, unscaled)
    scatter_gemm1_kernel<<<sbcnt + 782, 256, 0, stream>>>(
        ei, bucket_cur, buckets, E, sbcnt, x, w1h, w1l, y1, n);
    // K2-3: per-bucket CSR (scan folded into fill)
    csr_local_kernel<<<nbuck, 512, 0, stream>>>(buckets, bucket_cur, row_ptr, bsum, dinv, n);
    fill_bucket_kernel<<<nbuck, 512, 0, stream>>>(buckets, bucket_cur, row_ptr, bsum,
                                                  col, n, nbuck);
    // K4: agg1 (src-scaled) + gemm2 -> y2 (scaled)
    agg_gemm_kernel<128, true><<<fb, 256, 0, stream>>>(
        y1, row_ptr, col, dinv, b1, w2h, w2l, y2, n);
    // K5: agg2 + gemm3 -> y3 (scaled)
    agg_gemm_kernel<64, false><<<fb, 256, 0, stream>>>(
        y2, row_ptr, col, dinv, b2, w3h, w3l, y3, n);
    // K6: final aggregate -> d_out
    agg_final_kernel<<<(n + 3) / 4, 256, 0, stream>>>(
        y3, row_ptr, col, dinv, b3, (float*)d_out, n);
}